// Round 11
// baseline (430.462 us; speedup 1.0000x reference)
//
#include <hip/hip_runtime.h>

// Persistent fused 2-layer LSTM + FC + softmax for MI355X (gfx950).
// B=2048, T=256, H=64, IN=42. 512 blocks x 256 threads; block owns 4 rows.
//
// R11: merged-role waves. Each of the 4 waves owns h-slice [16w,16w+16) and
// computes BOTH layer0(t=i) and layer1(t=i-1) per iteration (their inputs are
// independent: L0 reads {x(i),h0(i-1)}, L1 reads {h0(i-1),h1(i-2)}, all in
// the cur ping-pong slot). 512 blocks -> 2 independent blocks/CU at
// 2 waves/SIMD (256-reg budget: B-frags 128 + acc 32 + A 32 + misc fits,
// unlike R9/R10's 128-reg squeeze which spilled 23 MB). One block's barrier
// drain is hidden by the other block's compute.
// Row map m = 4r: each lane's real cell is acc element [0] (static index),
// 1 cell per layer per lane. Peeled i=0 -> branch-free steady-state body.
// Arithmetic bitwise-identical to R8-R10 (same MFMA, k-order, f16 rounding).

typedef _Float16 f16;
typedef _Float16 f16x2 __attribute__((ext_vector_type(2)));
typedef _Float16 f16x8 __attribute__((ext_vector_type(8)));
typedef float f32x4 __attribute__((ext_vector_type(4)));

namespace {
constexpr int kT = 256;
constexpr int kIn = 42;
constexpr int kH = 64;
constexpr int kRows = 4;          // batch rows per block
constexpr int kThr = 256;
constexpr int kKP = 136;          // LDS row stride in f16 (272 B, 16B-aligned)
constexpr int kSlot = 16 * kKP;   // one ping-pong slot (f16 elems)
}

__device__ __forceinline__ float sig_(float v) {
  return __fdividef(1.0f, 1.0f + __expf(-v));
}
__device__ __forceinline__ float tnh_(float v) {
  return __fdividef(2.0f, 1.0f + __expf(-2.0f * v)) - 1.0f;
}

__global__ __launch_bounds__(kThr, 2)   // 2 waves/EU -> 2 blocks/CU, 256 regs
void lstm_mr_kernel(const float* __restrict__ x,
                    const float* __restrict__ Wih0, const float* __restrict__ Whh0,
                    const float* __restrict__ bih0, const float* __restrict__ bhh0,
                    const float* __restrict__ Wih1, const float* __restrict__ Whh1,
                    const float* __restrict__ bih1, const float* __restrict__ bhh1,
                    const float* __restrict__ Wfc, const float* __restrict__ bfc,
                    float* __restrict__ out) {
  // xh0 row m: [ x(t) (42) | h0 (64) | pad ]
  // xh1 row m: [ h0 (64) | h1 (64) | pad ]
  __shared__ __align__(16) f16 xh0[2 * kSlot];
  __shared__ __align__(16) f16 xh1[2 * kSlot];
  __shared__ float lg[kRows * 8];

  const int tid = threadIdx.x;
  const int w = tid >> 6;        // wave -> h-slice [16w, 16w+16)
  const int l = tid & 63;
  const int c = l & 15;
  const int quad = l >> 4;
  const int row0 = blockIdx.x * kRows;

  for (int i = tid; i < 2 * kSlot; i += kThr) { xh0[i] = (f16)0; xh1[i] = (f16)0; }

  // ---- one-time: BOTH layers' weights as MFMA B-fragments + biases ----
  f16x8 B0[4][4], B1[4][4];
  float bias0[4], bias1[4];
#pragma unroll
  for (int a = 0; a < 4; ++a) {
    const int g = (w + 4 * a) * 16 + c;
    bias0[a] = bih0[g] + bhh0[g];
    bias1[a] = bih1[g] + bhh1[g];
#pragma unroll
    for (int q = 0; q < 4; ++q) {
      f16x8 v0, v1;
#pragma unroll
      for (int j = 0; j < 8; ++j) {
        const int k = q * 32 + quad * 8 + j;
        const float w0v = (k < 42) ? Wih0[g * kIn + k]
                        : (k < 106) ? Whh0[g * kH + (k - 42)] : 0.f;
        const float w1v = (k < 64) ? Wih1[g * kH + k] : Whh1[g * kH + (k - 64)];
        v0[j] = (f16)w0v;
        v1[j] = (f16)w1v;
      }
      B0[a][q] = v0;
      B1[a][q] = v1;
    }
  }

  // Row map m = 4r: lane (quad,c)'s real cell is M-row 4*quad = batch row
  // quad, acc element [0], h-col 16w+c. One cell per layer per lane.
  float cst0 = 0.f, cst1 = 0.f;
  const int mym = 4 * quad;
  const int hcol = w * 16 + c;

  // x staging: 84 threads, one float2 each; batch row srr -> LDS row 4*srr
  const float* xbase = x + (size_t)row0 * kT * kIn;
  const bool stager = (tid < 84);
  const int srr = tid / 21;
  const int sp = tid - srr * 21;
  const int sm = 4 * srr;

  if (stager) {  // pre-stage x(0) into slot 0
    const float2 v = *(const float2*)(xbase + (size_t)srr * kT * kIn + 2 * sp);
    f16x2 hv; hv.x = (f16)v.x; hv.y = (f16)v.y;
    *(f16x2*)&xh0[sm * kKP + 2 * sp] = hv;
  }
  __syncthreads();

  const f16* ar0 = xh0 + c * kKP + quad * 8;
  const f16* ar1 = xh1 + c * kKP + quad * 8;

  // ---- peeled i=0: layer0(t=0) only, stage x(1) ----
  {
    f32x4 acc[4];
#pragma unroll
    for (int a = 0; a < 4; ++a) acc[a] = (f32x4){bias0[a], bias0[a], bias0[a], bias0[a]};
#pragma unroll
    for (int q = 0; q < 4; ++q) {
      const f16x8 A = __builtin_bit_cast(f16x8, *(const float4*)(ar0 + q * 32));
#pragma unroll
      for (int a = 0; a < 4; ++a)
        acc[a] = __builtin_amdgcn_mfma_f32_16x16x32_f16(A, B0[a][q], acc[a], 0, 0, 0);
    }
    const float gi = acc[0][0], gf = acc[1][0], gg = acc[2][0], go = acc[3][0];
    cst0 = sig_(gf) * cst0 + sig_(gi) * tnh_(gg);
    const f16 h = (f16)(sig_(go) * tnh_(cst0));
    xh0[kSlot + mym * kKP + 42 + hcol] = h;
    xh1[kSlot + mym * kKP + hcol] = h;
    if (stager) {
      const float2 v = *(const float2*)(xbase + (size_t)srr * kT * kIn + (size_t)1 * kIn + 2 * sp);
      f16x2 hv; hv.x = (f16)v.x; hv.y = (f16)v.y;
      *(f16x2*)&xh0[kSlot + sm * kKP + 2 * sp] = hv;
    }
  }
  __syncthreads();

  // ---- steady state: iter i computes L0(t=i) and L1(t=i-1), 1 barrier ----
  for (int i = 1; i <= kT; ++i) {
    const int cur = i & 1, nxt = cur ^ 1;

    float2 xv;
    if (stager) {
      const int tl = (i + 1 < kT) ? (i + 1) : (kT - 1);  // clamped (harmless re-stage at tail)
      xv = *(const float2*)(xbase + (size_t)srr * kT * kIn + (size_t)tl * kIn + 2 * sp);
    }

    // layer 0, t=i (at i==kT this computes garbage into dead state/regions)
    f32x4 acc0[4];
#pragma unroll
    for (int a = 0; a < 4; ++a) acc0[a] = (f32x4){bias0[a], bias0[a], bias0[a], bias0[a]};
#pragma unroll
    for (int q = 0; q < 4; ++q) {
      const f16x8 A = __builtin_bit_cast(f16x8, *(const float4*)(ar0 + cur * kSlot + q * 32));
#pragma unroll
      for (int a = 0; a < 4; ++a)
        acc0[a] = __builtin_amdgcn_mfma_f32_16x16x32_f16(A, B0[a][q], acc0[a], 0, 0, 0);
    }

    // layer 1, t=i-1
    f32x4 acc1[4];
#pragma unroll
    for (int a = 0; a < 4; ++a) acc1[a] = (f32x4){bias1[a], bias1[a], bias1[a], bias1[a]};
#pragma unroll
    for (int q = 0; q < 4; ++q) {
      const f16x8 A = __builtin_bit_cast(f16x8, *(const float4*)(ar1 + cur * kSlot + q * 32));
#pragma unroll
      for (int a = 0; a < 4; ++a)
        acc1[a] = __builtin_amdgcn_mfma_f32_16x16x32_f16(A, B1[a][q], acc1[a], 0, 0, 0);
    }

    // layer-0 cell update (static element [0])
    {
      const float gi = acc0[0][0], gf = acc0[1][0], gg = acc0[2][0], go = acc0[3][0];
      cst0 = sig_(gf) * cst0 + sig_(gi) * tnh_(gg);
      const f16 h = (f16)(sig_(go) * tnh_(cst0));
      xh0[nxt * kSlot + mym * kKP + 42 + hcol] = h;
      xh1[nxt * kSlot + mym * kKP + hcol] = h;
    }
    // layer-1 cell update (h1(i-1); at i==kT this is the final h1)
    {
      const float gi = acc1[0][0], gf = acc1[1][0], gg = acc1[2][0], go = acc1[3][0];
      cst1 = sig_(gf) * cst1 + sig_(gi) * tnh_(gg);
      xh1[nxt * kSlot + mym * kKP + 64 + hcol] = (f16)(sig_(go) * tnh_(cst1));
    }
    if (stager) {
      f16x2 hv; hv.x = (f16)xv.x; hv.y = (f16)xv.y;
      *(f16x2*)&xh0[nxt * kSlot + sm * kKP + 2 * sp] = hv;
    }
    __syncthreads();
  }

  // ---- FC + softmax. Final h1(T-1) written at i=kT into nxt=1 -> slot 1. ----
  if (tid < kRows * 5) {
    const int rr = tid / 5, oo = tid - rr * 5;
    const int m = 4 * rr;
    float a = bfc[oo];
#pragma unroll
    for (int j = 0; j < kH; ++j)
      a += (float)xh1[kSlot + m * kKP + 64 + j] * Wfc[oo * kH + j];
    lg[rr * 8 + oo] = a;
  }
  __syncthreads();
  if (tid < kRows) {
    const float v0 = lg[tid * 8 + 0], v1 = lg[tid * 8 + 1], v2 = lg[tid * 8 + 2],
                v3 = lg[tid * 8 + 3], v4 = lg[tid * 8 + 4];
    const float m = fmaxf(fmaxf(fmaxf(v0, v1), fmaxf(v2, v3)), v4);
    const float e0 = __expf(v0 - m), e1 = __expf(v1 - m), e2 = __expf(v2 - m),
                e3 = __expf(v3 - m), e4 = __expf(v4 - m);
    const float inv = __fdividef(1.0f, e0 + e1 + e2 + e3 + e4);
    float* o = out + (size_t)(row0 + tid) * 5;
    o[0] = e0 * inv; o[1] = e1 * inv; o[2] = e2 * inv; o[3] = e3 * inv; o[4] = e4 * inv;
  }
}

extern "C" void kernel_launch(void* const* d_in, const int* in_sizes, int n_in,
                              void* d_out, int out_size, void* d_ws, size_t ws_size,
                              hipStream_t stream) {
  (void)in_sizes; (void)n_in; (void)d_ws; (void)ws_size; (void)out_size;
  lstm_mr_kernel<<<dim3(512), dim3(kThr), 0, stream>>>(
      (const float*)d_in[0],
      (const float*)d_in[1], (const float*)d_in[2],
      (const float*)d_in[3], (const float*)d_in[4],
      (const float*)d_in[5], (const float*)d_in[6],
      (const float*)d_in[7], (const float*)d_in[8],
      (const float*)d_in[9], (const float*)d_in[10],
      (float*)d_out);
}